// Round 1
// baseline (183.411 us; speedup 1.0000x reference)
//
#include <hip/hip_runtime.h>

#define IMG_H 512
#define IMG_W 512
#define NGAUSS 10000
#define N_VIEWS 4
#define PATCH 40

__global__ __launch_bounds__(256) void gs_splat_kernel(
    const float* __restrict__ poses,
    const float* __restrict__ Km,
    const float* __restrict__ means,
    const float* __restrict__ log_scales,
    const float* __restrict__ quats,
    const float* __restrict__ shs,
    const float* __restrict__ opac,
    float* __restrict__ out)
{
    const int bid  = blockIdx.x;
    const int view = bid / NGAUSS;
    const int n    = bid - view * NGAUSS;

    // ---- per-gaussian preprocessing (redundant across threads; broadcast loads) ----
    const float* P = poses + view * 16;   // 4x4 row-major
    const float m0 = means[n * 3 + 0];
    const float m1 = means[n * 3 + 1];
    const float m2 = means[n * 3 + 2];

    // p_cam = Rm @ mean + t   (Rm = P[:3,:3], t = P[:3,3])
    const float Xc = P[0] * m0 + P[1] * m1 + P[2]  * m2 + P[3];
    const float Yc = P[4] * m0 + P[5] * m1 + P[6]  * m2 + P[7];
    const float Zc = P[8] * m0 + P[9] * m1 + P[10] * m2 + P[11];

    // p_proj = K @ p_cam
    const float ppx = Km[0] * Xc + Km[1] * Yc + Km[2] * Zc;
    const float ppy = Km[3] * Xc + Km[4] * Yc + Km[5] * Zc;
    const float ppz = Km[6] * Xc + Km[7] * Yc + Km[8] * Zc;

    const float denom = ppz + 1e-8f;
    const float uvx = ppx / denom;
    const float uvy = ppy / denom;

    const int u = (int)uvx;   // trunc toward zero, matches jnp.trunc + int32 cast
    const int v = (int)uvy;

    const bool valid = (Zc >= 0.1f) && (u >= 0) && (u < IMG_W) && (v >= 0) && (v < IMG_H);
    if (!valid) return;   // block-uniform

    // quaternion -> rotation (rows 0,1 are all we need for the 2x2 cov block)
    const float qw = quats[n * 4 + 0];
    const float qx = quats[n * 4 + 1];
    const float qy = quats[n * 4 + 2];
    const float qz = quats[n * 4 + 3];
    const float R00 = 1.0f - 2.0f * (qy * qy + qz * qz);
    const float R01 = 2.0f * (qx * qy - qw * qz);
    const float R02 = 2.0f * (qx * qz + qw * qy);
    const float R10 = 2.0f * (qx * qy + qw * qz);
    const float R11 = 1.0f - 2.0f * (qx * qx + qz * qz);
    const float R12 = 2.0f * (qy * qz - qw * qx);

    const float s0 = expf(log_scales[n * 3 + 0]);
    const float s1 = expf(log_scales[n * 3 + 1]);
    const float s2 = expf(log_scales[n * 3 + 2]);

    // cov2x2 = R[0:2,:] diag(s) R[0:2,:]^T
    const float a = R00 * R00 * s0 + R01 * R01 * s1 + R02 * R02 * s2;
    const float b = R00 * R10 * s0 + R01 * R11 * s1 + R02 * R12 * s2;
    const float d = R10 * R10 * s0 + R11 * R11 * s1 + R12 * R12 * s2;

    const float det = a * d - b * b;
    const float i00 =  d / det;
    const float i01 = -b / det;
    const float i11 =  a / det;

    // premultiplied color: sigmoid(op) * sigmoid(sh_dc)
    const float op = 1.0f / (1.0f + expf(-opac[n]));
    const float w0 = op / (1.0f + expf(-shs[n * 48 +  0]));
    const float w1 = op / (1.0f + expf(-shs[n * 48 + 16]));
    const float w2 = op / (1.0f + expf(-shs[n * 48 + 32]));

    float* img = out + (size_t)view * IMG_H * IMG_W * 3;

    // ---- patch evaluation ----
    for (int pix = threadIdx.x; pix < PATCH * PATCH; pix += 256) {
        const int iy = pix / PATCH;
        const int ix = pix - iy * PATCH;
        const int yy = v - PATCH / 2 + iy;
        const int xx = u - PATCH / 2 + ix;
        if (yy < 0 || yy >= IMG_H || xx < 0 || xx >= IMG_W) continue;

        const float dx = (float)xx - uvx;
        const float dy = (float)yy - uvy;
        const float q  = dx * (i00 * dx + i01 * dy) + dy * (i01 * dx + i11 * dy);
        float expo = -0.5f * q;
        expo = fminf(fmaxf(expo, -10.0f), 0.0f);
        const float g = expf(expo);

        if (g > 0.001f) {
            float* p = img + ((size_t)yy * IMG_W + xx) * 3;
            atomicAdd(p + 0, g * w0);
            atomicAdd(p + 1, g * w1);
            atomicAdd(p + 2, g * w2);
        }
    }
}

extern "C" void kernel_launch(void* const* d_in, const int* in_sizes, int n_in,
                              void* d_out, int out_size, void* d_ws, size_t ws_size,
                              hipStream_t stream) {
    const float* poses      = (const float*)d_in[0];
    const float* intrinsics = (const float*)d_in[1];
    const float* means      = (const float*)d_in[2];
    const float* log_scales = (const float*)d_in[3];
    const float* quats      = (const float*)d_in[4];
    const float* shs        = (const float*)d_in[5];
    const float* opac       = (const float*)d_in[6];
    float* out = (float*)d_out;

    // harness poisons d_out with 0xAA before every launch — zero it
    hipMemsetAsync(out, 0, (size_t)out_size * sizeof(float), stream);

    dim3 grid(N_VIEWS * NGAUSS);
    gs_splat_kernel<<<grid, 256, 0, stream>>>(
        poses, intrinsics, means, log_scales, quats, shs, opac, out);
}

// Round 2
// 100.412 us; speedup vs baseline: 1.8266x; 1.8266x over previous
//
#include <hip/hip_runtime.h>

#define IMG_H 512
#define IMG_W 512
#define NGAUSS 10000
#define N_VIEWS 4
#define PATCH 40
#define TOTAL_G (N_VIEWS * NGAUSS)

// -2 * ln(0.001): g > 0.001  <=>  q < QMAX  (given the -10 clip makes g even smaller)
#define QMAX 13.815511f

__global__ __launch_bounds__(256) void zero_kernel(float4* __restrict__ out, int n4) {
    int i = blockIdx.x * 256 + threadIdx.x;
    if (i < n4) out[i] = make_float4(0.f, 0.f, 0.f, 0.f);
}

// One 64-lane wave per (view, gaussian). 4 waves per block.
__global__ __launch_bounds__(256) void gs_splat_kernel(
    const float* __restrict__ poses,
    const float* __restrict__ Km,
    const float* __restrict__ means,
    const float* __restrict__ log_scales,
    const float* __restrict__ quats,
    const float* __restrict__ shs,
    const float* __restrict__ opac,
    float* __restrict__ out)
{
    const int wid = (blockIdx.x << 2) + (threadIdx.x >> 6);
    if (wid >= TOTAL_G) return;
    const int lane = threadIdx.x & 63;
    const int view = wid / NGAUSS;
    const int n    = wid - view * NGAUSS;

    // ---- per-gaussian preprocessing (redundant across the wave; broadcast loads) ----
    const float* P = poses + view * 16;   // 4x4 row-major
    const float m0 = means[n * 3 + 0];
    const float m1 = means[n * 3 + 1];
    const float m2 = means[n * 3 + 2];

    const float Xc = P[0] * m0 + P[1] * m1 + P[2]  * m2 + P[3];
    const float Yc = P[4] * m0 + P[5] * m1 + P[6]  * m2 + P[7];
    const float Zc = P[8] * m0 + P[9] * m1 + P[10] * m2 + P[11];

    const float ppx = Km[0] * Xc + Km[1] * Yc + Km[2] * Zc;
    const float ppy = Km[3] * Xc + Km[4] * Yc + Km[5] * Zc;
    const float ppz = Km[6] * Xc + Km[7] * Yc + Km[8] * Zc;

    const float denom = ppz + 1e-8f;
    const float uvx = ppx / denom;
    const float uvy = ppy / denom;

    const int u = (int)uvx;   // trunc, matches jnp.trunc + int32 cast
    const int v = (int)uvy;

    if (!((Zc >= 0.1f) && (u >= 0) && (u < IMG_W) && (v >= 0) && (v < IMG_H)))
        return;   // wave-uniform

    const float qw = quats[n * 4 + 0];
    const float qx = quats[n * 4 + 1];
    const float qy = quats[n * 4 + 2];
    const float qz = quats[n * 4 + 3];
    const float R00 = 1.0f - 2.0f * (qy * qy + qz * qz);
    const float R01 = 2.0f * (qx * qy - qw * qz);
    const float R02 = 2.0f * (qx * qz + qw * qy);
    const float R10 = 2.0f * (qx * qy + qw * qz);
    const float R11 = 1.0f - 2.0f * (qx * qx + qz * qz);
    const float R12 = 2.0f * (qy * qz - qw * qx);

    const float s0 = expf(log_scales[n * 3 + 0]);
    const float s1 = expf(log_scales[n * 3 + 1]);
    const float s2 = expf(log_scales[n * 3 + 2]);

    // cov2x2 = R[0:2,:] diag(s) R[0:2,:]^T
    const float a = R00 * R00 * s0 + R01 * R01 * s1 + R02 * R02 * s2;
    const float b = R00 * R10 * s0 + R01 * R11 * s1 + R02 * R12 * s2;
    const float d = R10 * R10 * s0 + R11 * R11 * s1 + R12 * R12 * s2;

    const float det = a * d - b * b;
    const float i00 =  d / det;
    const float i01 = -b / det;
    const float i11 =  a / det;

    // ---- tight window: ellipse q <= QMAX has |dx| <= sqrt(QMAX*cov00), |dy| <= sqrt(QMAX*cov11)
    // +0.5 px inflation makes fp rounding harmless; exact g>0.001 test is still applied per pixel.
    const float rx = sqrtf(QMAX * a) + 0.5f;
    const float ry = sqrtf(QMAX * d) + 0.5f;

    int xlo = (int)ceilf (uvx - rx);
    int xhi = (int)floorf(uvx + rx);
    int ylo = (int)ceilf (uvy - ry);
    int yhi = (int)floorf(uvy + ry);
    // patch bounds (reference only evaluates xx in [u-20, u+19]) and image bounds
    xlo = max(xlo, max(u - PATCH / 2, 0));
    xhi = min(xhi, min(u + PATCH / 2 - 1, IMG_W - 1));
    ylo = max(ylo, max(v - PATCH / 2, 0));
    yhi = min(yhi, min(v + PATCH / 2 - 1, IMG_H - 1));

    const int wx = xhi - xlo + 1;
    const int wy = yhi - ylo + 1;
    if (wx <= 0 || wy <= 0) return;
    const int area = wx * wy;

    const float op = 1.0f / (1.0f + expf(-opac[n]));
    const float w0 = op / (1.0f + expf(-shs[n * 48 +  0]));
    const float w1 = op / (1.0f + expf(-shs[n * 48 + 16]));
    const float w2 = op / (1.0f + expf(-shs[n * 48 + 32]));

    float* img = out + (size_t)view * IMG_H * IMG_W * 3;

    for (int p = lane; p < area; p += 64) {
        const int iy = p / wx;
        const int ix = p - iy * wx;
        const int yy = ylo + iy;
        const int xx = xlo + ix;

        const float dx = (float)xx - uvx;
        const float dy = (float)yy - uvy;
        const float q  = dx * (i00 * dx + i01 * dy) + dy * (i01 * dx + i11 * dy);
        float expo = -0.5f * q;
        expo = fminf(fmaxf(expo, -10.0f), 0.0f);
        const float g = expf(expo);

        if (g > 0.001f) {
            float* pp = img + ((size_t)yy * IMG_W + xx) * 3;
            atomicAdd(pp + 0, g * w0);
            atomicAdd(pp + 1, g * w1);
            atomicAdd(pp + 2, g * w2);
        }
    }
}

extern "C" void kernel_launch(void* const* d_in, const int* in_sizes, int n_in,
                              void* d_out, int out_size, void* d_ws, size_t ws_size,
                              hipStream_t stream) {
    const float* poses      = (const float*)d_in[0];
    const float* intrinsics = (const float*)d_in[1];
    const float* means      = (const float*)d_in[2];
    const float* log_scales = (const float*)d_in[3];
    const float* quats      = (const float*)d_in[4];
    const float* shs        = (const float*)d_in[5];
    const float* opac       = (const float*)d_in[6];
    float* out = (float*)d_out;

    // zero the output (harness poisons with 0xAA); out_size = 4*512*512*3, divisible by 4
    const int n4 = out_size / 4;
    zero_kernel<<<(n4 + 255) / 256, 256, 0, stream>>>((float4*)out, n4);

    // 4 waves per block, one wave per (view, gaussian)
    const int nblocks = (TOTAL_G + 3) / 4;
    gs_splat_kernel<<<nblocks, 256, 0, stream>>>(
        poses, intrinsics, means, log_scales, quats, shs, opac, out);
}

// Round 3
// 93.757 us; speedup vs baseline: 1.9562x; 1.0710x over previous
//
#include <hip/hip_runtime.h>

#define IMG_H 512
#define IMG_W 512
#define NGAUSS 10000
#define N_VIEWS 4
#define PATCH 40
#define TOTAL_G (N_VIEWS * NGAUSS)

// -2 * ln(0.001): g > 0.001  <=>  q < QMAX (given the -10 clip only shrinks g)
#define QMAX 13.815511f

struct __align__(16) Desc {
    float uvx, uvy, i00, i01;
    float i11, w0, w1, w2;
    int xlo, ylo, wx, area;   // area==0 => skip
};

// Phase 1: one THREAD per (view,gaussian) builds a splat descriptor; the same
// kernel grid-strides a float4 zero over the output image (harness poisons 0xAA).
__global__ __launch_bounds__(256) void gs_prep_kernel(
    const float* __restrict__ poses,
    const float* __restrict__ Km,
    const float* __restrict__ means,
    const float* __restrict__ log_scales,
    const float* __restrict__ quats,
    const float* __restrict__ shs,
    const float* __restrict__ opac,
    Desc* __restrict__ descs,
    float4* __restrict__ out4, int n4)
{
    const int tid = blockIdx.x * 256 + threadIdx.x;

    // fused output zeroing
    for (int i = tid; i < n4; i += gridDim.x * 256)
        out4[i] = make_float4(0.f, 0.f, 0.f, 0.f);

    if (tid >= TOTAL_G) return;
    const int view = tid / NGAUSS;
    const int n    = tid - view * NGAUSS;

    const float* P = poses + view * 16;
    const float m0 = means[n * 3 + 0];
    const float m1 = means[n * 3 + 1];
    const float m2 = means[n * 3 + 2];

    const float Xc = P[0] * m0 + P[1] * m1 + P[2]  * m2 + P[3];
    const float Yc = P[4] * m0 + P[5] * m1 + P[6]  * m2 + P[7];
    const float Zc = P[8] * m0 + P[9] * m1 + P[10] * m2 + P[11];

    const float ppx = Km[0] * Xc + Km[1] * Yc + Km[2] * Zc;
    const float ppy = Km[3] * Xc + Km[4] * Yc + Km[5] * Zc;
    const float ppz = Km[6] * Xc + Km[7] * Yc + Km[8] * Zc;

    const float denom = ppz + 1e-8f;
    const float uvx = ppx / denom;
    const float uvy = ppy / denom;

    const int u = (int)uvx;   // trunc, matches jnp.trunc + int32 cast
    const int v = (int)uvy;

    Desc d;
    d.area = 0;

    if ((Zc >= 0.1f) && (u >= 0) && (u < IMG_W) && (v >= 0) && (v < IMG_H)) {
        const float qw = quats[n * 4 + 0];
        const float qx = quats[n * 4 + 1];
        const float qy = quats[n * 4 + 2];
        const float qz = quats[n * 4 + 3];
        const float R00 = 1.0f - 2.0f * (qy * qy + qz * qz);
        const float R01 = 2.0f * (qx * qy - qw * qz);
        const float R02 = 2.0f * (qx * qz + qw * qy);
        const float R10 = 2.0f * (qx * qy + qw * qz);
        const float R11 = 1.0f - 2.0f * (qx * qx + qz * qz);
        const float R12 = 2.0f * (qy * qz - qw * qx);

        const float s0 = expf(log_scales[n * 3 + 0]);
        const float s1 = expf(log_scales[n * 3 + 1]);
        const float s2 = expf(log_scales[n * 3 + 2]);

        const float a = R00 * R00 * s0 + R01 * R01 * s1 + R02 * R02 * s2;
        const float b = R00 * R10 * s0 + R01 * R11 * s1 + R02 * R12 * s2;
        const float dd = R10 * R10 * s0 + R11 * R11 * s1 + R12 * R12 * s2;

        const float det = a * dd - b * b;
        d.i00 =  dd / det;
        d.i01 = -b  / det;
        d.i11 =  a  / det;

        // tight ellipse bbox, +0.5 px safety; exact g>0.001 still tested per pixel
        const float rx = sqrtf(QMAX * a)  + 0.5f;
        const float ry = sqrtf(QMAX * dd) + 0.5f;

        int xlo = (int)ceilf (uvx - rx);
        int xhi = (int)floorf(uvx + rx);
        int ylo = (int)ceilf (uvy - ry);
        int yhi = (int)floorf(uvy + ry);
        xlo = max(xlo, max(u - PATCH / 2, 0));
        xhi = min(xhi, min(u + PATCH / 2 - 1, IMG_W - 1));
        ylo = max(ylo, max(v - PATCH / 2, 0));
        yhi = min(yhi, min(v + PATCH / 2 - 1, IMG_H - 1));

        const int wx = xhi - xlo + 1;
        const int wy = yhi - ylo + 1;
        if (wx > 0 && wy > 0) {
            const float op = 1.0f / (1.0f + expf(-opac[n]));
            d.w0 = op / (1.0f + expf(-shs[n * 48 +  0]));
            d.w1 = op / (1.0f + expf(-shs[n * 48 + 16]));
            d.w2 = op / (1.0f + expf(-shs[n * 48 + 32]));
            d.uvx = uvx; d.uvy = uvy;
            d.xlo = xlo; d.ylo = ylo; d.wx = wx;
            d.area = wx * wy;
        }
    }

    if (d.area == 0) {   // keep stores fully defined / deterministic
        d.uvx = d.uvy = d.i00 = d.i01 = d.i11 = d.w0 = d.w1 = d.w2 = 0.f;
        d.xlo = d.ylo = d.wx = 0;
    }
    descs[tid] = d;
}

// Phase 2: 32 lanes per splat (2 splats per wave, 8 per block).
__global__ __launch_bounds__(256) void gs_splat_kernel(
    const Desc* __restrict__ descs,
    float* __restrict__ out)
{
    const int gtid = blockIdx.x * 256 + threadIdx.x;
    const int sid  = gtid >> 5;
    if (sid >= TOTAL_G) return;
    const int sub  = threadIdx.x & 31;

    const Desc d = descs[sid];
    if (d.area == 0) return;

    const int view = sid / NGAUSS;
    float* img = out + (size_t)view * IMG_H * IMG_W * 3;

    for (int p = sub; p < d.area; p += 32) {
        const int iy = p / d.wx;
        const int ix = p - iy * d.wx;
        const int yy = d.ylo + iy;
        const int xx = d.xlo + ix;

        const float dx = (float)xx - d.uvx;
        const float dy = (float)yy - d.uvy;
        const float q  = dx * (d.i00 * dx + d.i01 * dy) + dy * (d.i01 * dx + d.i11 * dy);
        float expo = -0.5f * q;
        expo = fminf(fmaxf(expo, -10.0f), 0.0f);
        const float g = expf(expo);

        if (g > 0.001f) {
            float* pp = img + ((size_t)yy * IMG_W + xx) * 3;
            atomicAdd(pp + 0, g * d.w0);
            atomicAdd(pp + 1, g * d.w1);
            atomicAdd(pp + 2, g * d.w2);
        }
    }
}

extern "C" void kernel_launch(void* const* d_in, const int* in_sizes, int n_in,
                              void* d_out, int out_size, void* d_ws, size_t ws_size,
                              hipStream_t stream) {
    const float* poses      = (const float*)d_in[0];
    const float* intrinsics = (const float*)d_in[1];
    const float* means      = (const float*)d_in[2];
    const float* log_scales = (const float*)d_in[3];
    const float* quats      = (const float*)d_in[4];
    const float* shs        = (const float*)d_in[5];
    const float* opac       = (const float*)d_in[6];
    float* out  = (float*)d_out;
    Desc* descs = (Desc*)d_ws;   // 40000 * 48 B = 1.92 MB << ws_size

    const int n4 = out_size / 4;                 // 786432 float4s
    const int prep_blocks = (n4 + 255) / 256;    // covers zeroing in one stride + all descs
    gs_prep_kernel<<<prep_blocks, 256, 0, stream>>>(
        poses, intrinsics, means, log_scales, quats, shs, opac,
        descs, (float4*)out, n4);

    const int splat_blocks = (TOTAL_G * 32 + 255) / 256;   // 5000
    gs_splat_kernel<<<splat_blocks, 256, 0, stream>>>(descs, out);
}